// Round 2
// baseline (847.226 us; speedup 1.0000x reference)
//
#include <hip/hip_runtime.h>
#include <hip/hip_fp16.h>

#define MEM  1024
#define B_   128
#define L_   512
#define M_   (B_*L_)      // 65536 rows
#define N_   (2*MEM)      // 2048 cols
#define K_   512

#define SCALE_U 16.0f
#define SCALE_W 1024.0f
#define INV_SCALE (1.0f / (16.0f * 1024.0f))

typedef __attribute__((ext_vector_type(8))) _Float16 half8;
typedef __attribute__((ext_vector_type(4))) float f32x4;

__device__ __forceinline__ float fast_tanh(float x) {
    float e = __expf(2.0f * x);
    return 1.0f - 2.0f / (e + 1.0f);
}
__device__ __forceinline__ float fast_sigmoid(float x) {
    return 1.0f / (1.0f + __expf(-x));
}
__device__ __forceinline__ void gl_lds16(const void* g, void* l) {
    __builtin_amdgcn_global_load_lds(
        (const __attribute__((address_space(1))) void*)g,
        (__attribute__((address_space(3))) void*)l, 16, 0, 0);
}

// fp32 -> scaled (hi fp16 RNE, lo fp16 = RNE(x*s - hi)); unbiased 2-way split.
__global__ void split_fp32_fp16x2(const float* __restrict__ in,
                                  unsigned short* __restrict__ hi,
                                  unsigned short* __restrict__ lo,
                                  int n4, float scale) {
    int i = blockIdx.x * 256 + threadIdx.x;
    if (i >= n4) return;
    const float4 v = reinterpret_cast<const float4*>(in)[i];
    float vs[4] = {v.x, v.y, v.z, v.w};
    unsigned short hs_[4], ls_[4];
#pragma unroll
    for (int c = 0; c < 4; ++c) {
        float xs = vs[c] * scale;
        __half h = __float2half_rn(xs);
        float r = xs - __half2float(h);
        __half l = __float2half_rn(r);
        hs_[c] = __half_as_ushort(h);
        ls_[c] = __half_as_ushort(l);
    }
    ushort4 h4, l4;
    h4.x = hs_[0]; h4.y = hs_[1]; h4.z = hs_[2]; h4.w = hs_[3];
    l4.x = ls_[0]; l4.y = ls_[1]; l4.z = ls_[2]; l4.w = ls_[3];
    reinterpret_cast<ushort4*>(hi)[i] = h4;
    reinterpret_cast<ushort4*>(lo)[i] = l4;
}

// Paired-half GEMM, fp32-A staged directly (split to fp16 hi/lo in VALU).
// R6: counted-vmcnt double-buffered pipeline (T3 + T4 + T5):
//   BM=256 (x2 col-halves of 128), BK=32, 512 threads (8 waves: 4 wm x 2 wn),
//   128 KB LDS (2 buffers). Each STAGE = 8 global_load_lds per thread.
//   Steady state waits s_waitcnt vmcnt(8) -- NEVER 0 -- so the next tile's
//   8 loads stay in flight across both barriers (m218: counted-vs-drain0
//   was the entire pipeline gain; R5's vmcnt(0) drain was the regression).
//   Peeled tail for tiles 14/15 where the wait must drop 8 -> 0.
// Swizzles unchanged from the verified R4/R5 kernels:
//   A: 16B chunks slot-swizzled slot = chunk ^ (row&7) (global-source side)
//   B: fp16, q2 XOR swizzle
#define TM 256
#define TN 128
#define BK 32
__global__ __launch_bounds__(512, 2) void gemm_paired_kernel(
    const float* __restrict__ u,
    const unsigned short* __restrict__ wh, const unsigned short* __restrict__ wl,
    const float* __restrict__ bias,
    float* __restrict__ z_out) {   // M_ x MEM
    __shared__ __attribute__((aligned(16))) float Af[2][TM * BK];            // 2 x 32 KB
    __shared__ __attribute__((aligned(16))) unsigned short Bh0[2][TN * BK];  // 2 x 8 KB
    __shared__ __attribute__((aligned(16))) unsigned short Bl0[2][TN * BK];
    __shared__ __attribute__((aligned(16))) unsigned short Bh1[2][TN * BK];
    __shared__ __attribute__((aligned(16))) unsigned short Bl1[2][TN * BK];

    const int tid = threadIdx.x;
    // supertile: group of 64 blocks = 8 M-tiles (fast) x 8 N-tiles.
    // ids {x, x+8, ..., x+56} share an A panel and land on the same XCD
    // (id%8 = XCD round-robin) -> A reuse is L2-local.
    const int id  = blockIdx.x;                  // 0..2047
    const int mt  = (id >> 6) * 8 + (id & 7);    // 0..255
    const int nt  = (id >> 3) & 7;               // 0..7
    const int tileM = mt * TM;
    const int tileN = nt * TN;

    const int lane = tid & 63, w = tid >> 6;
    const int wm = w & 3, wn = w >> 2;           // 4 M-chunks x 2 N-chunks of 64
    const int lrow = lane & 15, quad = lane >> 4;
    const int q2 = quad ^ ((lrow >> 1) & 3);     // B bank-conflict XOR swizzle

    f32x4 acc0[4][4] = {};
    f32x4 acc1[4][4] = {};

    // A staging: 4 calls of 512 lanes x 16B cover 256x32 floats.
    size_t aoff[4];
#pragma unroll
    for (int c = 0; c < 4; ++c) {
        const int p = c * 512 + tid;          // LDS chunk index
        const int row = p >> 3;
        const int chunk = (p & 7) ^ (row & 7);
        aoff[c] = (size_t)(tileM + row) * K_ + chunk * 4;
    }
    // B staging: 1 chunk (16B = 8 shorts) per array per thread, q2-swizzled source.
    const int rB = tid >> 2;                       // 0..127
    const int gsB = (tid & 3) ^ ((rB >> 1) & 3);
    const size_t sB0 = (size_t)(tileN + rB) * K_ + gsB * 8;
    const size_t sB1 = (size_t)(tileN + 1024 + rB) * K_ + gsB * 8;

#define STAGE(BUF, KT) do {                                               \
        const size_t ko_ = (size_t)(KT) * BK;                             \
        _Pragma("unroll")                                                 \
        for (int c = 0; c < 4; ++c)                                       \
            gl_lds16(u + aoff[c] + ko_, &Af[BUF][(c * 512 + tid) * 4]);   \
        gl_lds16(wh + sB0 + ko_, &Bh0[BUF][tid * 8]);                     \
        gl_lds16(wl + sB0 + ko_, &Bl0[BUF][tid * 8]);                     \
        gl_lds16(wh + sB1 + ko_, &Bh1[BUF][tid * 8]);                     \
        gl_lds16(wl + sB1 + ko_, &Bl1[BUF][tid * 8]);                     \
    } while (0)

#define COMPUTE(BUF) do {                                                            \
        half8 ahf[4], alf[4];                                                        \
        _Pragma("unroll")                                                            \
        for (int i = 0; i < 4; ++i) {                                                \
            const int r = wm * 64 + i * 16 + lrow;                                   \
            const int sw = r & 7;                                                    \
            const f32x4 t0 = *(const f32x4*)&Af[BUF][(r * 8 + ((quad * 2)     ^ sw)) * 4]; \
            const f32x4 t1 = *(const f32x4*)&Af[BUF][(r * 8 + ((quad * 2 + 1) ^ sw)) * 4]; \
            half8 h, l;                                                              \
            _Pragma("unroll")                                                        \
            for (int e = 0; e < 4; ++e) {                                            \
                float xs = t0[e] * SCALE_U;                                          \
                _Float16 hh = (_Float16)xs;                                          \
                h[e] = hh;                                                           \
                l[e] = (_Float16)(xs - (float)hh);                                   \
                xs = t1[e] * SCALE_U;                                                \
                hh = (_Float16)xs;                                                   \
                h[e + 4] = hh;                                                       \
                l[e + 4] = (_Float16)(xs - (float)hh);                               \
            }                                                                        \
            ahf[i] = h; alf[i] = l;                                                  \
        }                                                                            \
        __builtin_amdgcn_s_setprio(1);                                               \
        _Pragma("unroll")                                                            \
        for (int j = 0; j < 4; ++j) {                                                \
            const int bo = ((wn * 64 + j * 16 + lrow) * 4 + q2) * 8;                 \
            const half8 b0h = *(const half8*)&Bh0[BUF][bo];                          \
            const half8 b0l = *(const half8*)&Bl0[BUF][bo];                          \
            const half8 b1h = *(const half8*)&Bh1[BUF][bo];                          \
            const half8 b1l = *(const half8*)&Bl1[BUF][bo];                          \
            _Pragma("unroll")                                                        \
            for (int i = 0; i < 4; ++i) {                                            \
                f32x4 c0 = acc0[i][j];                                               \
                c0 = __builtin_amdgcn_mfma_f32_16x16x32_f16(ahf[i], b0h, c0, 0, 0, 0); \
                c0 = __builtin_amdgcn_mfma_f32_16x16x32_f16(ahf[i], b0l, c0, 0, 0, 0); \
                c0 = __builtin_amdgcn_mfma_f32_16x16x32_f16(alf[i], b0h, c0, 0, 0, 0); \
                acc0[i][j] = c0;                                                     \
                f32x4 c1 = acc1[i][j];                                               \
                c1 = __builtin_amdgcn_mfma_f32_16x16x32_f16(ahf[i], b1h, c1, 0, 0, 0); \
                c1 = __builtin_amdgcn_mfma_f32_16x16x32_f16(ahf[i], b1l, c1, 0, 0, 0); \
                c1 = __builtin_amdgcn_mfma_f32_16x16x32_f16(alf[i], b1h, c1, 0, 0, 0); \
                acc1[i][j] = c1;                                                     \
            }                                                                        \
        }                                                                            \
        __builtin_amdgcn_s_setprio(0);                                               \
    } while (0)

    // Prologue: both buffers' loads in flight (16 per thread).
    STAGE(0, 0);
    STAGE(1, 1);

    // Counted-vmcnt main loop: wait leaves the newest 8 loads (next buffer)
    // in flight; each buffer's loads get a full MFMA phase of latency cover.
    // Per-wave load FIFO: wait vmcnt(8) == "all but the 8 newest are done".
#pragma unroll 1
    for (int kt = 0; kt <= 12; kt += 2) {
        asm volatile("s_waitcnt vmcnt(8)" ::: "memory");   // buf0[kt] ready; buf1 flying
        __builtin_amdgcn_s_barrier();
        COMPUTE(0);
        __builtin_amdgcn_s_barrier();                      // all waves done reading buf0
        STAGE(0, kt + 2);                                  // kt+2 <= 14
        asm volatile("s_waitcnt vmcnt(8)" ::: "memory");   // buf1[kt+1] ready; buf0 flying
        __builtin_amdgcn_s_barrier();
        COMPUTE(1);
        __builtin_amdgcn_s_barrier();                      // all waves done reading buf1
        STAGE(1, kt + 3);                                  // kt+3 <= 15
    }
    // Peeled tail: tiles 14 (buf0) and 15 (buf1); no restaging, so the wait
    // counts must drop to 8 then 0 (vmcnt(8) with 8 outstanding would not wait).
    asm volatile("s_waitcnt vmcnt(8)" ::: "memory");
    __builtin_amdgcn_s_barrier();
    COMPUTE(0);
    asm volatile("s_waitcnt vmcnt(0)" ::: "memory");
    __builtin_amdgcn_s_barrier();
    COMPUTE(1);

    // Epilogue: fused z = 5*tanh((c1+b1)/5) + (c2+b2).
#pragma unroll
    for (int j = 0; j < 4; ++j) {
        const int c = tileN + wn * 64 + j * 16 + lrow;
        const float b1v = bias[c];
        const float b2v = bias[c + 1024];
#pragma unroll
        for (int i = 0; i < 4; ++i) {
            const int rowb = tileM + wm * 64 + i * 16 + quad * 4;
#pragma unroll
            for (int r = 0; r < 4; ++r) {
                float v1 = acc0[i][j][r] * INV_SCALE + b1v;
                v1 = fast_tanh(v1 * 0.2f) * 5.0f;
                const float v2 = acc1[i][j][r] * INV_SCALE + b2v;
                z_out[(size_t)(rowb + r) * MEM + c] = v1 + v2;
            }
        }
    }
#undef STAGE
#undef COMPUTE
}

// One thread per (b, m) chain; 16-deep register prefetch (4 KB/wave in flight).
__global__ __launch_bounds__(256) void scan_kernel(
    const float* __restrict__ z,      // M_ x MEM fused io+sb
    float* __restrict__ h_t,          // out: hf sequence
    const float* __restrict__ h0,
    float* __restrict__ hf_last) {
    const int idx = blockIdx.x * 256 + threadIdx.x;   // 0 .. 131071
    const int b = idx >> 10, m = idx & (MEM - 1);
    float hf = h0[idx];
    float hs = h0[B_ * MEM + idx];
    const size_t base = (size_t)b * L_ * MEM + m;

    float zv[16], zn[16];
#pragma unroll
    for (int j = 0; j < 16; ++j) zv[j] = z[base + (size_t)j * MEM];

    for (int l0 = 0; l0 < L_; l0 += 16) {
        const bool more = (l0 + 16) < L_;
        if (more) {
#pragma unroll
            for (int j = 0; j < 16; ++j)
                zn[j] = z[base + (size_t)(l0 + 16 + j) * MEM];
        }
#pragma unroll
        for (int j = 0; j < 16; ++j) {
            const float hsb = hs + 0.4f;
            const float x = zv[j] + 4.0f * hf - 7.0f * hsb * hsb;
            const float hfn = fast_tanh(x);
            const float eps = 0.9f + 0.9f * fast_sigmoid(10.0f * (hf - 0.5f));
            hs = hs + eps * (hf - hs);
            h_t[base + (size_t)(l0 + j) * MEM] = hfn;
            hf = hfn;
        }
        if (more) {
#pragma unroll
            for (int j = 0; j < 16; ++j) zv[j] = zn[j];
        }
    }
    hf_last[idx] = hf;
}

extern "C" void kernel_launch(void* const* d_in, const int* in_sizes, int n_in,
                              void* d_out, int out_size, void* d_ws, size_t ws_size,
                              hipStream_t stream) {
    const float* u    = (const float*)d_in[0];   // (128,512,512)
    const float* h0   = (const float*)d_in[1];   // (2,128,1024)
    const float* W_im = (const float*)d_in[2];   // (2048,512)
    const float* b_im = (const float*)d_in[3];   // (2048,)

    float* out = (float*)d_out;
    float* h_t = out;
    float* hf_last = out + (size_t)M_ * MEM;

    // ws layout (~273 MB):
    //   z   : M_*MEM fp32      = 268,435,456 B
    //   wh  : N_*K_  fp16      =   2,097,152 B
    //   wl  : N_*K_  fp16      =   2,097,152 B
    char* ws = (char*)d_ws;
    float* z           = (float*)ws;
    unsigned short* wh = (unsigned short*)(ws + 268435456ull);
    unsigned short* wl = (unsigned short*)(ws + 270532608ull);

    // 1) split W fp32 -> fp16 hi/lo (scaled)
    {
        const int n4_w = (N_ * K_) / 4;
        split_fp32_fp16x2<<<(n4_w + 255) / 256, 256, 0, stream>>>(W_im, wh, wl, n4_w, SCALE_W);
    }
    // 2) paired GEMM (fp32-A on-the-fly split, counted-vmcnt dbuf) -> fused z
    {
        gemm_paired_kernel<<<2048, 512, 0, stream>>>(u, wh, wl, b_im, z);
    }
    // 3) recurrence scan + hf_last
    {
        scan_kernel<<<(B_ * MEM) / 256, 256, 0, stream>>>(z, h_t, h0, hf_last);
    }
}

// Round 3
// 782.351 us; speedup vs baseline: 1.0829x; 1.0829x over previous
//
#include <hip/hip_runtime.h>
#include <hip/hip_fp16.h>

#define MEM  1024
#define B_   128
#define L_   512
#define M_   (B_*L_)      // 65536 rows
#define N_   (2*MEM)      // 2048 cols
#define K_   512

#define SCALE_U 16.0f
#define SCALE_W 1024.0f
#define INV_SCALE (1.0f / (16.0f * 1024.0f))

typedef __attribute__((ext_vector_type(8))) _Float16 half8;
typedef __attribute__((ext_vector_type(4))) float f32x4;

__device__ __forceinline__ float fast_tanh(float x) {
    float e = __expf(2.0f * x);
    return 1.0f - 2.0f / (e + 1.0f);
}
__device__ __forceinline__ float fast_sigmoid(float x) {
    return 1.0f / (1.0f + __expf(-x));
}
__device__ __forceinline__ void gl_lds16(const void* g, void* l) {
    __builtin_amdgcn_global_load_lds(
        (const __attribute__((address_space(1))) void*)g,
        (__attribute__((address_space(3))) void*)l, 16, 0, 0);
}

// fp32 -> scaled (hi fp16 RNE, lo fp16 = RNE(x*s - hi)); unbiased 2-way split.
// Only used for W (4 MB); u is split on the fly inside the GEMM.
__global__ void split_fp32_fp16x2(const float* __restrict__ in,
                                  unsigned short* __restrict__ hi,
                                  unsigned short* __restrict__ lo,
                                  int n4, float scale) {
    int i = blockIdx.x * 256 + threadIdx.x;
    if (i >= n4) return;
    const float4 v = reinterpret_cast<const float4*>(in)[i];
    float vs[4] = {v.x, v.y, v.z, v.w};
    unsigned short hs_[4], ls_[4];
#pragma unroll
    for (int c = 0; c < 4; ++c) {
        float xs = vs[c] * scale;
        __half h = __float2half_rn(xs);
        float r = xs - __half2float(h);
        __half l = __float2half_rn(r);
        hs_[c] = __half_as_ushort(h);
        ls_[c] = __half_as_ushort(l);
    }
    ushort4 h4, l4;
    h4.x = hs_[0]; h4.y = hs_[1]; h4.z = hs_[2]; h4.w = hs_[3];
    l4.x = ls_[0]; l4.y = ls_[1]; l4.z = ls_[2]; l4.w = ls_[3];
    reinterpret_cast<ushort4*>(hi)[i] = h4;
    reinterpret_cast<ushort4*>(lo)[i] = l4;
}

// Paired-half GEMM, fp32-A staged directly (split to fp16 hi/lo in VALU).
// R7: verbatim revert to the proven R0/R4 structure (430 us, MfmaUtil 44%):
//   TM=128, 256 threads, 2 blocks/CU -- implicit dual-block overlap at the
//   barrier beats both explicit pipeline attempts (R5 drain / R6 counted
//   vmcnt, both 505 us: hipcc's legalizer re-inserts conservative waits
//   before ds_read after global_load_lds, defeating source-level vmcnt).
// z = 5*tanh((c1+b1)/5) + (c2+b2) written fused.
// A LDS: 128 rows x 32 floats, 16B chunks slot-swizzled: slot = chunk ^ (row&7)
// B LDS: fp16, q2 XOR swizzle (conflict-free verified).
#define TM 128
#define TN 128
#define BK 32
__global__ __launch_bounds__(256, 2) void gemm_paired_kernel(
    const float* __restrict__ u,
    const unsigned short* __restrict__ wh, const unsigned short* __restrict__ wl,
    const float* __restrict__ bias,
    float* __restrict__ z_out) {   // M_ x MEM
    __shared__ __attribute__((aligned(16))) float Af[TM * BK];            // 16 KB
    __shared__ __attribute__((aligned(16))) unsigned short Bh0[TN * BK];  // 8 KB
    __shared__ __attribute__((aligned(16))) unsigned short Bl0[TN * BK];
    __shared__ __attribute__((aligned(16))) unsigned short Bh1[TN * BK];
    __shared__ __attribute__((aligned(16))) unsigned short Bl1[TN * BK];

    const int tid = threadIdx.x;
    // supertile: group of 64 blocks = 8 M-tiles (fast) x 8 N-pairs
    const int id  = blockIdx.x;                  // 0..4095
    const int mt  = (id >> 6) * 8 + (id & 7);    // 0..511
    const int nt  = (id >> 3) & 7;               // 0..7
    const int tileM = mt * TM;
    const int tileN = nt * TN;

    const int lane = tid & 63, w = tid >> 6;
    const int wm = w & 1, wn = w >> 1;
    const int lrow = lane & 15, quad = lane >> 4;
    const int q2 = quad ^ ((lrow >> 1) & 3);     // B bank-conflict XOR swizzle

    f32x4 acc0[4][4] = {};
    f32x4 acc1[4][4] = {};

    // A staging: 4 calls of 256 lanes x 16B cover 128x32 floats.
    size_t aoff[4];
#pragma unroll
    for (int c = 0; c < 4; ++c) {
        const int p = c * 256 + tid;          // LDS chunk index
        const int row = p >> 3;
        const int chunk = (p & 7) ^ (row & 7);
        aoff[c] = (size_t)(tileM + row) * K_ + chunk * 4;
    }
    // B staging (fp16, 2 chunks per tile per thread), q2-swizzled source.
    const int i0 = tid, i1 = tid + 256;
    const int r0 = i0 >> 2, gs0 = (i0 & 3) ^ ((r0 >> 1) & 3);
    const int r1 = i1 >> 2, gs1 = (i1 & 3) ^ ((r1 >> 1) & 3);
    const size_t sB0a = (size_t)(tileN + r0) * K_ + gs0 * 8;
    const size_t sB0b = (size_t)(tileN + r1) * K_ + gs1 * 8;
    const size_t sB1a = (size_t)(tileN + 1024 + r0) * K_ + gs0 * 8;
    const size_t sB1b = (size_t)(tileN + 1024 + r1) * K_ + gs1 * 8;

    for (int kt = 0; kt < K_ / BK; ++kt) {
        const size_t ko = (size_t)kt * BK;     // k-elements (floats for u, shorts for w)
        __syncthreads();
#pragma unroll
        for (int c = 0; c < 4; ++c)
            gl_lds16(u + aoff[c] + ko, &Af[c * 1024 + tid * 4]);
        gl_lds16(wh + sB0a + ko, &Bh0[i0 * 8]);
        gl_lds16(wh + sB0b + ko, &Bh0[i1 * 8]);
        gl_lds16(wl + sB0a + ko, &Bl0[i0 * 8]);
        gl_lds16(wl + sB0b + ko, &Bl0[i1 * 8]);
        gl_lds16(wh + sB1a + ko, &Bh1[i0 * 8]);
        gl_lds16(wh + sB1b + ko, &Bh1[i1 * 8]);
        gl_lds16(wl + sB1a + ko, &Bl1[i0 * 8]);
        gl_lds16(wl + sB1b + ko, &Bl1[i1 * 8]);
        __syncthreads();

        // A fragments: read fp32, split to fp16 hi/lo in VALU.
        half8 ahf[4], alf[4];
#pragma unroll
        for (int i = 0; i < 4; ++i) {
            const int r = wm * 64 + i * 16 + lrow;
            const int sw = r & 7;
            const f32x4 t0 = *(const f32x4*)&Af[(r * 8 + ((quad * 2)     ^ sw)) * 4];
            const f32x4 t1 = *(const f32x4*)&Af[(r * 8 + ((quad * 2 + 1) ^ sw)) * 4];
            half8 h, l;
#pragma unroll
            for (int e = 0; e < 4; ++e) {
                float xs = t0[e] * SCALE_U;
                _Float16 hh = (_Float16)xs;
                h[e] = hh;
                l[e] = (_Float16)(xs - (float)hh);
                xs = t1[e] * SCALE_U;
                hh = (_Float16)xs;
                h[e + 4] = hh;
                l[e + 4] = (_Float16)(xs - (float)hh);
            }
            ahf[i] = h; alf[i] = l;
        }
#pragma unroll
        for (int j = 0; j < 4; ++j) {
            const int bo = ((wn * 64 + j * 16 + lrow) * 4 + q2) * 8;
            const half8 b0h = *(const half8*)&Bh0[bo];
            const half8 b0l = *(const half8*)&Bl0[bo];
            const half8 b1h = *(const half8*)&Bh1[bo];
            const half8 b1l = *(const half8*)&Bl1[bo];
#pragma unroll
            for (int i = 0; i < 4; ++i) {
                f32x4 c0 = acc0[i][j];
                c0 = __builtin_amdgcn_mfma_f32_16x16x32_f16(ahf[i], b0h, c0, 0, 0, 0);
                c0 = __builtin_amdgcn_mfma_f32_16x16x32_f16(ahf[i], b0l, c0, 0, 0, 0);
                c0 = __builtin_amdgcn_mfma_f32_16x16x32_f16(alf[i], b0h, c0, 0, 0, 0);
                acc0[i][j] = c0;
                f32x4 c1 = acc1[i][j];
                c1 = __builtin_amdgcn_mfma_f32_16x16x32_f16(ahf[i], b1h, c1, 0, 0, 0);
                c1 = __builtin_amdgcn_mfma_f32_16x16x32_f16(ahf[i], b1l, c1, 0, 0, 0);
                c1 = __builtin_amdgcn_mfma_f32_16x16x32_f16(alf[i], b1h, c1, 0, 0, 0);
                acc1[i][j] = c1;
            }
        }
    }

    // Epilogue: fused z = 5*tanh((c1+b1)/5) + (c2+b2).
#pragma unroll
    for (int j = 0; j < 4; ++j) {
        const int c = tileN + wn * 64 + j * 16 + lrow;
        const float b1v = bias[c];
        const float b2v = bias[c + 1024];
#pragma unroll
        for (int i = 0; i < 4; ++i) {
            const int rowb = tileM + wm * 64 + i * 16 + quad * 4;
#pragma unroll
            for (int r = 0; r < 4; ++r) {
                float v1 = acc0[i][j][r] * INV_SCALE + b1v;
                v1 = fast_tanh(v1 * 0.2f) * 5.0f;
                const float v2 = acc1[i][j][r] * INV_SCALE + b2v;
                z_out[(size_t)(rowb + r) * MEM + c] = v1 + v2;
            }
        }
    }
}

// R7 scan: 2 chains per thread (float2 loads/stores, 8B/lane), 65536 threads
// = 256 blocks x 256 -> exactly 1 block/CU, 4 waves/CU (one per SIMD), 2-way
// ILP on the dependent tanh/sigmoid chain. Unroll-2 double buffer with NO
// bulk register copy: zb0/zb1 alternate compute/prefetch roles, so the
// compiler's per-use wait leaves the newer stores + refill loads in flight
// (the old zv=zn copy forced a near-drain each block, serializing on store
// retirement). Math per chain is op-for-op identical -> bit-identical h_t.
__global__ __launch_bounds__(256) void scan_kernel(
    const float* __restrict__ z,      // M_ x MEM fused io+sb
    float* __restrict__ h_t,          // out: hf sequence
    const float* __restrict__ h0,
    float* __restrict__ hf_last) {
    const int idx = blockIdx.x * 256 + threadIdx.x;   // 0 .. 65535
    const int b  = idx >> 9;                          // 512 float2-chains per b
    const int m  = (idx & 511) * 2;                   // even m
    const size_t base = ((size_t)b * L_ * MEM + m) >> 1;   // float2 index
    const float2* z2  = (const float2*)z;
    float2* h2        = (float2*)h_t;

    const int hidx = (b * MEM + m) >> 1;              // float2 index into h0 maps
    float2 hf = ((const float2*)h0)[hidx];
    float2 hs = ((const float2*)h0)[(B_ * MEM) / 2 + hidx];

    const size_t STRIDE = MEM / 2;                    // float2 stride per l

    float2 zb0[16], zb1[16];
#pragma unroll
    for (int j = 0; j < 16; ++j) zb0[j] = z2[base + (size_t)j * STRIDE];

#define STEP(ZB, J, LL) do {                                              \
        const float2 zv_ = (ZB)[J];                                       \
        float2 o_;                                                        \
        {   const float hsb = hs.x + 0.4f;                                \
            const float x_  = zv_.x + 4.0f * hf.x - 7.0f * hsb * hsb;     \
            const float hfn = fast_tanh(x_);                              \
            const float eps = 0.9f + 0.9f * fast_sigmoid(10.0f * (hf.x - 0.5f)); \
            hs.x = hs.x + eps * (hf.x - hs.x);                            \
            o_.x = hfn; hf.x = hfn; }                                     \
        {   const float hsb = hs.y + 0.4f;                                \
            const float x_  = zv_.y + 4.0f * hf.y - 7.0f * hsb * hsb;     \
            const float hfn = fast_tanh(x_);                              \
            const float eps = 0.9f + 0.9f * fast_sigmoid(10.0f * (hf.y - 0.5f)); \
            hs.y = hs.y + eps * (hf.y - hs.y);                            \
            o_.y = hfn; hf.y = hfn; }                                     \
        h2[base + (size_t)(LL) * STRIDE] = o_;                            \
    } while (0)

#pragma unroll 1
    for (int l0 = 0; l0 < L_; l0 += 32) {
        // prefetch block B1 = [l0+16, l0+32): always in range (l0 <= 480)
#pragma unroll
        for (int j = 0; j < 16; ++j)
            zb1[j] = z2[base + (size_t)(l0 + 16 + j) * STRIDE];
        // compute block B0 = [l0, l0+16)
#pragma unroll
        for (int j = 0; j < 16; ++j) STEP(zb0, j, l0 + j);
        // prefetch block B0' = [l0+32, l0+48)
        if (l0 + 32 < L_) {
#pragma unroll
            for (int j = 0; j < 16; ++j)
                zb0[j] = z2[base + (size_t)(l0 + 32 + j) * STRIDE];
        }
        // compute block B1
#pragma unroll
        for (int j = 0; j < 16; ++j) STEP(zb1, j, l0 + 16 + j);
    }
#undef STEP

    ((float2*)hf_last)[hidx] = hf;
}

extern "C" void kernel_launch(void* const* d_in, const int* in_sizes, int n_in,
                              void* d_out, int out_size, void* d_ws, size_t ws_size,
                              hipStream_t stream) {
    const float* u    = (const float*)d_in[0];   // (128,512,512)
    const float* h0   = (const float*)d_in[1];   // (2,128,1024)
    const float* W_im = (const float*)d_in[2];   // (2048,512)
    const float* b_im = (const float*)d_in[3];   // (2048,)

    float* out = (float*)d_out;
    float* h_t = out;
    float* hf_last = out + (size_t)M_ * MEM;

    // ws layout (~273 MB):
    //   z   : M_*MEM fp32      = 268,435,456 B
    //   wh  : N_*K_  fp16      =   2,097,152 B
    //   wl  : N_*K_  fp16      =   2,097,152 B
    char* ws = (char*)d_ws;
    float* z           = (float*)ws;
    unsigned short* wh = (unsigned short*)(ws + 268435456ull);
    unsigned short* wl = (unsigned short*)(ws + 270532608ull);

    // 1) split W fp32 -> fp16 hi/lo (scaled)
    {
        const int n4_w = (N_ * K_) / 4;
        split_fp32_fp16x2<<<(n4_w + 255) / 256, 256, 0, stream>>>(W_im, wh, wl, n4_w, SCALE_W);
    }
    // 2) paired GEMM (fp32-A on-the-fly split) -> fused z
    {
        gemm_paired_kernel<<<4096, 256, 0, stream>>>(u, wh, wl, b_im, z);
    }
    // 3) recurrence scan + hf_last (2 chains/thread, float2)
    {
        scan_kernel<<<(B_ * MEM) / 512, 256, 0, stream>>>(z, h_t, h0, hf_last);
    }
}

// Round 6
// 781.725 us; speedup vs baseline: 1.0838x; 1.0008x over previous
//
#include <hip/hip_runtime.h>
#include <hip/hip_fp16.h>

#define MEM  1024
#define B_   128
#define L_   512
#define M_   (B_*L_)      // 65536 rows
#define N_   (2*MEM)      // 2048 cols
#define K_   512

#define SCALE_U 16.0f
#define SCALE_W 1024.0f
#define INV_SCALE (1.0f / (16.0f * 1024.0f))

typedef __attribute__((ext_vector_type(8))) _Float16 half8;
typedef __attribute__((ext_vector_type(4))) float f32x4;

__device__ __forceinline__ float fast_tanh(float x) {
    float e = __expf(2.0f * x);
    return 1.0f - 2.0f / (e + 1.0f);
}
__device__ __forceinline__ float fast_sigmoid(float x) {
    return 1.0f / (1.0f + __expf(-x));
}
__device__ __forceinline__ void gl_lds16(const void* g, void* l) {
    __builtin_amdgcn_global_load_lds(
        (const __attribute__((address_space(1))) void*)g,
        (__attribute__((address_space(3))) void*)l, 16, 0, 0);
}

// fp32 -> scaled (hi fp16 RNE, lo fp16 = RNE(x*s - hi)); unbiased 2-way split.
__global__ void split_fp32_fp16x2(const float* __restrict__ in,
                                  unsigned short* __restrict__ hi,
                                  unsigned short* __restrict__ lo,
                                  int n4, float scale) {
    int i = blockIdx.x * 256 + threadIdx.x;
    if (i >= n4) return;
    const float4 v = reinterpret_cast<const float4*>(in)[i];
    float vs[4] = {v.x, v.y, v.z, v.w};
    unsigned short hs_[4], ls_[4];
#pragma unroll
    for (int c = 0; c < 4; ++c) {
        float xs = vs[c] * scale;
        __half h = __float2half_rn(xs);
        float r = xs - __half2float(h);
        __half l = __float2half_rn(r);
        hs_[c] = __half_as_ushort(h);
        ls_[c] = __half_as_ushort(l);
    }
    ushort4 h4, l4;
    h4.x = hs_[0]; h4.y = hs_[1]; h4.z = hs_[2]; h4.w = hs_[3];
    l4.x = ls_[0]; l4.y = ls_[1]; l4.z = ls_[2]; l4.w = ls_[3];
    reinterpret_cast<ushort4*>(hi)[i] = h4;
    reinterpret_cast<ushort4*>(lo)[i] = l4;
}

// Paired-half GEMM (proven R0 structure, 44% MfmaUtil). R10: takes m_base and
// is launched TWICE with grid 2048 (M halves) so the scan kernel becomes the
// longest dispatch and surfaces in rocprof top-5 (we still have no scan
// counters; its ~337 us defies BW/latency/issue models by 4x).
// A LDS: 16B chunks slot-swizzled slot = chunk ^ (row&7); B: q2 XOR swizzle.
#define TM 128
#define TN 128
#define BK 32
__global__ __launch_bounds__(256, 2) void gemm_paired_kernel(
    const float* __restrict__ u,
    const unsigned short* __restrict__ wh, const unsigned short* __restrict__ wl,
    const float* __restrict__ bias,
    float* __restrict__ z_out,
    int m_base) {   // M_ x MEM
    __shared__ __attribute__((aligned(16))) float Af[TM * BK];            // 16 KB
    __shared__ __attribute__((aligned(16))) unsigned short Bh0[TN * BK];  // 8 KB
    __shared__ __attribute__((aligned(16))) unsigned short Bl0[TN * BK];
    __shared__ __attribute__((aligned(16))) unsigned short Bh1[TN * BK];
    __shared__ __attribute__((aligned(16))) unsigned short Bl1[TN * BK];

    const int tid = threadIdx.x;
    // supertile: group of 64 blocks = 8 M-tiles (fast) x 8 N-pairs
    const int id  = blockIdx.x;                  // 0..2047
    const int mt  = (id >> 6) * 8 + (id & 7);    // 0..255
    const int nt  = (id >> 3) & 7;               // 0..7
    const int tileM = m_base + mt * TM;
    const int tileN = nt * TN;

    const int lane = tid & 63, w = tid >> 6;
    const int wm = w & 1, wn = w >> 1;
    const int lrow = lane & 15, quad = lane >> 4;
    const int q2 = quad ^ ((lrow >> 1) & 3);     // B bank-conflict XOR swizzle

    f32x4 acc0[4][4] = {};
    f32x4 acc1[4][4] = {};

    // A staging: 4 calls of 256 lanes x 16B cover 128x32 floats.
    size_t aoff[4];
#pragma unroll
    for (int c = 0; c < 4; ++c) {
        const int p = c * 256 + tid;          // LDS chunk index
        const int row = p >> 3;
        const int chunk = (p & 7) ^ (row & 7);
        aoff[c] = (size_t)(tileM + row) * K_ + chunk * 4;
    }
    // B staging (fp16, 2 chunks per tile per thread), q2-swizzled source.
    const int i0 = tid, i1 = tid + 256;
    const int r0 = i0 >> 2, gs0 = (i0 & 3) ^ ((r0 >> 1) & 3);
    const int r1 = i1 >> 2, gs1 = (i1 & 3) ^ ((r1 >> 1) & 3);
    const size_t sB0a = (size_t)(tileN + r0) * K_ + gs0 * 8;
    const size_t sB0b = (size_t)(tileN + r1) * K_ + gs1 * 8;
    const size_t sB1a = (size_t)(tileN + 1024 + r0) * K_ + gs0 * 8;
    const size_t sB1b = (size_t)(tileN + 1024 + r1) * K_ + gs1 * 8;

    for (int kt = 0; kt < K_ / BK; ++kt) {
        const size_t ko = (size_t)kt * BK;     // k-elements (floats for u, shorts for w)
        __syncthreads();
#pragma unroll
        for (int c = 0; c < 4; ++c)
            gl_lds16(u + aoff[c] + ko, &Af[c * 1024 + tid * 4]);
        gl_lds16(wh + sB0a + ko, &Bh0[i0 * 8]);
        gl_lds16(wh + sB0b + ko, &Bh0[i1 * 8]);
        gl_lds16(wl + sB0a + ko, &Bl0[i0 * 8]);
        gl_lds16(wl + sB0b + ko, &Bl0[i1 * 8]);
        gl_lds16(wh + sB1a + ko, &Bh1[i0 * 8]);
        gl_lds16(wh + sB1b + ko, &Bh1[i1 * 8]);
        gl_lds16(wl + sB1a + ko, &Bl1[i0 * 8]);
        gl_lds16(wl + sB1b + ko, &Bl1[i1 * 8]);
        __syncthreads();

        // A fragments: read fp32, split to fp16 hi/lo in VALU.
        half8 ahf[4], alf[4];
#pragma unroll
        for (int i = 0; i < 4; ++i) {
            const int r = wm * 64 + i * 16 + lrow;
            const int sw = r & 7;
            const f32x4 t0 = *(const f32x4*)&Af[(r * 8 + ((quad * 2)     ^ sw)) * 4];
            const f32x4 t1 = *(const f32x4*)&Af[(r * 8 + ((quad * 2 + 1) ^ sw)) * 4];
            half8 h, l;
#pragma unroll
            for (int e = 0; e < 4; ++e) {
                float xs = t0[e] * SCALE_U;
                _Float16 hh = (_Float16)xs;
                h[e] = hh;
                l[e] = (_Float16)(xs - (float)hh);
                xs = t1[e] * SCALE_U;
                hh = (_Float16)xs;
                h[e + 4] = hh;
                l[e + 4] = (_Float16)(xs - (float)hh);
            }
            ahf[i] = h; alf[i] = l;
        }
#pragma unroll
        for (int j = 0; j < 4; ++j) {
            const int bo = ((wn * 64 + j * 16 + lrow) * 4 + q2) * 8;
            const half8 b0h = *(const half8*)&Bh0[bo];
            const half8 b0l = *(const half8*)&Bl0[bo];
            const half8 b1h = *(const half8*)&Bh1[bo];
            const half8 b1l = *(const half8*)&Bl1[bo];
#pragma unroll
            for (int i = 0; i < 4; ++i) {
                f32x4 c0 = acc0[i][j];
                c0 = __builtin_amdgcn_mfma_f32_16x16x32_f16(ahf[i], b0h, c0, 0, 0, 0);
                c0 = __builtin_amdgcn_mfma_f32_16x16x32_f16(ahf[i], b0l, c0, 0, 0, 0);
                c0 = __builtin_amdgcn_mfma_f32_16x16x32_f16(alf[i], b0h, c0, 0, 0, 0);
                acc0[i][j] = c0;
                f32x4 c1 = acc1[i][j];
                c1 = __builtin_amdgcn_mfma_f32_16x16x32_f16(ahf[i], b1h, c1, 0, 0, 0);
                c1 = __builtin_amdgcn_mfma_f32_16x16x32_f16(ahf[i], b1l, c1, 0, 0, 0);
                c1 = __builtin_amdgcn_mfma_f32_16x16x32_f16(alf[i], b1h, c1, 0, 0, 0);
                acc1[i][j] = c1;
            }
        }
    }

    // Epilogue: fused z = 5*tanh((c1+b1)/5) + (c2+b2).
#pragma unroll
    for (int j = 0; j < 4; ++j) {
        const int c = tileN + wn * 64 + j * 16 + lrow;
        const float b1v = bias[c];
        const float b2v = bias[c + 1024];
#pragma unroll
        for (int i = 0; i < 4; ++i) {
            const int rowb = tileM + wm * 64 + i * 16 + quad * 4;
#pragma unroll
            for (int r = 0; r < 4; ++r) {
                float v1 = acc0[i][j][r] * INV_SCALE + b1v;
                v1 = fast_tanh(v1 * 0.2f) * 5.0f;
                const float v2 = acc1[i][j][r] * INV_SCALE + b2v;
                z_out[(size_t)(rowb + r) * MEM + c] = v1 + v2;
            }
        }
    }
}

// R10 scan: VERBATIM the R7 scan that passed at 782 us (2 chains/thread,
// float2, 2-buffer alternation, no bulk copy). The untested 4-buffer R8
// variant is dropped: it was the only substantive untested code in the two
// consecutive container failures.
__global__ __launch_bounds__(256) void scan_kernel(
    const float* __restrict__ z,      // M_ x MEM fused io+sb
    float* __restrict__ h_t,          // out: hf sequence
    const float* __restrict__ h0,
    float* __restrict__ hf_last) {
    const int idx = blockIdx.x * 256 + threadIdx.x;   // 0 .. 65535
    const int b  = idx >> 9;                          // 512 float2-chains per b
    const int m  = (idx & 511) * 2;                   // even m
    const size_t base = ((size_t)b * L_ * MEM + m) >> 1;   // float2 index
    const float2* z2  = (const float2*)z;
    float2* h2        = (float2*)h_t;

    const int hidx = (b * MEM + m) >> 1;              // float2 index into h0 maps
    float2 hf = ((const float2*)h0)[hidx];
    float2 hs = ((const float2*)h0)[(B_ * MEM) / 2 + hidx];

    const size_t STRIDE = MEM / 2;                    // float2 stride per l

    float2 zb0[16], zb1[16];
#pragma unroll
    for (int j = 0; j < 16; ++j) zb0[j] = z2[base + (size_t)j * STRIDE];

#define STEP(ZB, J, LL) do {                                              \
        const float2 zv_ = (ZB)[J];                                       \
        float2 o_;                                                        \
        {   const float hsb = hs.x + 0.4f;                                \
            const float x_  = zv_.x + 4.0f * hf.x - 7.0f * hsb * hsb;     \
            const float hfn = fast_tanh(x_);                              \
            const float eps = 0.9f + 0.9f * fast_sigmoid(10.0f * (hf.x - 0.5f)); \
            hs.x = hs.x + eps * (hf.x - hs.x);                            \
            o_.x = hfn; hf.x = hfn; }                                     \
        {   const float hsb = hs.y + 0.4f;                                \
            const float x_  = zv_.y + 4.0f * hf.y - 7.0f * hsb * hsb;     \
            const float hfn = fast_tanh(x_);                              \
            const float eps = 0.9f + 0.9f * fast_sigmoid(10.0f * (hf.y - 0.5f)); \
            hs.y = hs.y + eps * (hf.y - hs.y);                            \
            o_.y = hfn; hf.y = hfn; }                                     \
        h2[base + (size_t)(LL) * STRIDE] = o_;                            \
    } while (0)

#pragma unroll 1
    for (int l0 = 0; l0 < L_; l0 += 32) {
        // prefetch block B1 = [l0+16, l0+32): always in range (l0 <= 480)
#pragma unroll
        for (int j = 0; j < 16; ++j)
            zb1[j] = z2[base + (size_t)(l0 + 16 + j) * STRIDE];
        // compute block B0 = [l0, l0+16)
#pragma unroll
        for (int j = 0; j < 16; ++j) STEP(zb0, j, l0 + j);
        // prefetch block B0' = [l0+32, l0+48)
        if (l0 + 32 < L_) {
#pragma unroll
            for (int j = 0; j < 16; ++j)
                zb0[j] = z2[base + (size_t)(l0 + 32 + j) * STRIDE];
        }
        // compute block B1
#pragma unroll
        for (int j = 0; j < 16; ++j) STEP(zb1, j, l0 + 16 + j);
    }
#undef STEP

    ((float2*)hf_last)[hidx] = hf;
}

extern "C" void kernel_launch(void* const* d_in, const int* in_sizes, int n_in,
                              void* d_out, int out_size, void* d_ws, size_t ws_size,
                              hipStream_t stream) {
    const float* u    = (const float*)d_in[0];   // (128,512,512)
    const float* h0   = (const float*)d_in[1];   // (2,128,1024)
    const float* W_im = (const float*)d_in[2];   // (2048,512)
    const float* b_im = (const float*)d_in[3];   // (2048,)

    float* out = (float*)d_out;
    float* h_t = out;
    float* hf_last = out + (size_t)M_ * MEM;

    // ws layout (~273 MB):
    //   z   : M_*MEM fp32      = 268,435,456 B
    //   wh  : N_*K_  fp16      =   2,097,152 B
    //   wl  : N_*K_  fp16      =   2,097,152 B
    char* ws = (char*)d_ws;
    float* z           = (float*)ws;
    unsigned short* wh = (unsigned short*)(ws + 268435456ull);
    unsigned short* wl = (unsigned short*)(ws + 270532608ull);

    // 1) split W fp32 -> fp16 hi/lo (scaled)
    {
        const int n4_w = (N_ * K_) / 4;
        split_fp32_fp16x2<<<(n4_w + 255) / 256, 256, 0, stream>>>(W_im, wh, wl, n4_w, SCALE_W);
    }
    // 2) paired GEMM in two M-half dispatches (~218 us each) so the scan
    //    becomes the longest dispatch and surfaces in rocprof top-5.
    {
        gemm_paired_kernel<<<2048, 256, 0, stream>>>(u, wh, wl, b_im, z, 0);
        gemm_paired_kernel<<<2048, 256, 0, stream>>>(u, wh, wl, b_im, z, M_ / 2);
    }
    // 3) recurrence scan + hf_last (2 chains/thread, float2)
    {
        scan_kernel<<<(B_ * MEM) / 512, 256, 0, stream>>>(z, h_t, h0, hf_last);
    }
}